// Round 5
// baseline (506.327 us; speedup 1.0000x reference)
//
#include <hip/hip_runtime.h>
#include <hip/hip_bf16.h>
#include <stdint.h>

#define D_DIM 1024
#define B_DIM 8
#define T_DIM 2048
#define M_DIM (B_DIM * T_DIM)  // 16384
#define CHUNK 32
#define NCHUNK (T_DIM / CHUNK)  // 64
#define NCH (B_DIM * D_DIM)     // 8192 channels

typedef unsigned short us;
typedef __attribute__((ext_vector_type(8))) short bf16x8;
typedef __attribute__((ext_vector_type(4))) float f32x4;

__device__ __forceinline__ us f2bf(float f) {
    union { float f; uint32_t u; } c; c.f = f;
    uint32_t u = c.u;
    u += 0x7fffu + ((u >> 16) & 1u);
    return (us)(u >> 16);
}
__device__ __forceinline__ float bf2f(us h) {
    union { uint32_t u; float f; } c; c.u = ((uint32_t)h) << 16;
    return c.f;
}

__device__ __forceinline__ void gload_lds16(const us* g, us* lds_base) {
    __builtin_amdgcn_global_load_lds(
        (const __attribute__((address_space(1))) unsigned int*)g,
        (__attribute__((address_space(3))) unsigned int*)lds_base, 16, 0, 0);
}

// ---- fused weight prep: WfT[g*1024+n][d] = bf16(Wg[d][n]*mix_g[d]),
//      WfT[g*1024+n][1024+d] = bf16(Wg[d][n]*(1-mix_g[d]))  (g = k,v,r) ----
__global__ void prep_weights(const float* __restrict__ Wk,
                             const float* __restrict__ Wv,
                             const float* __restrict__ Wr,
                             const float* __restrict__ tmk,
                             const float* __restrict__ tmv,
                             const float* __restrict__ tmr,
                             us* __restrict__ WfT) {
    int g = blockIdx.z;
    const float* W = (g == 0) ? Wk : (g == 1) ? Wv : Wr;
    const float* mix = (g == 0) ? tmk : (g == 1) ? tmv : tmr;
    __shared__ float tile[32][33];
    int tx = threadIdx.x, ty = threadIdx.y;
    int x0 = blockIdx.x * 32, y0 = blockIdx.y * 32;  // x0 -> n, y0 -> d
#pragma unroll
    for (int i = 0; i < 4; i++) {
        int r = ty + i * 8;
        tile[r][tx] = W[(size_t)(y0 + r) * D_DIM + x0 + tx];
    }
    __syncthreads();
    float mx = mix[y0 + tx];
#pragma unroll
    for (int i = 0; i < 4; i++) {
        int r = ty + i * 8;
        int n = g * 1024 + x0 + r;
        int d = y0 + tx;
        float w = tile[tx][r];  // = W[d][n]
        WfT[(size_t)n * 2048 + d] = f2bf(w * mx);
        WfT[(size_t)n * 2048 + 1024 + d] = f2bf(w * (1.0f - mx));
    }
}

// ---- Wo [K,N] fp32 -> WoT [N,K] bf16 ----
__global__ void transpose_wo(const float* __restrict__ W,
                             us* __restrict__ WT) {
    __shared__ float tile[32][33];
    int tx = threadIdx.x, ty = threadIdx.y;
    int x0 = blockIdx.x * 32, y0 = blockIdx.y * 32;
#pragma unroll
    for (int i = 0; i < 4; i++) {
        int r = ty + i * 8;
        tile[r][tx] = W[(size_t)(y0 + r) * D_DIM + x0 + tx];
    }
    __syncthreads();
#pragma unroll
    for (int i = 0; i < 4; i++) {
        int r = ty + i * 8;
        WT[(size_t)(x0 + r) * D_DIM + y0 + tx] = f2bf(tile[tx][r]);
    }
}

// ---- xall[b][0]=bf16(last_x[b]); xall[b][1+t]=bf16(x[b][t]); rows=B*(T+1) ----
__global__ void cast_x(const float* __restrict__ x,
                       const float* __restrict__ last_x,
                       us* __restrict__ xall) {
    int row = blockIdx.x;             // 0 .. 8*2049-1
    int b = row / (T_DIM + 1);
    int t = row - b * (T_DIM + 1);
    const float* src = (t == 0) ? (last_x + (size_t)b * D_DIM)
                                : (x + ((size_t)b * T_DIM + t - 1) * D_DIM);
    int c = threadIdx.x * 4;
    float4 v = *(const float4*)(src + c);
    ushort4 o;
    o.x = f2bf(v.x); o.y = f2bf(v.y); o.z = f2bf(v.z); o.w = f2bf(v.w);
    *(ushort4*)(xall + (size_t)row * D_DIM + c) = o;
}

// ---- fused GEMM1: C[M,3072] = [x , xshift] (M x 2048) * WfT^T ----
// n-group 0,1 (k,v) -> kvout bf16 stride 2048; group 2 (r) -> sigmoid -> rout
__global__ __launch_bounds__(256) void gemm_fused(
    const us* __restrict__ xall,
    const us* __restrict__ WfT,
    us* __restrict__ kvout,
    us* __restrict__ rout) {
    __shared__ __align__(16) us As[2][128 * 32];
    __shared__ __align__(16) us Bs[2][128 * 32];
    int tid = threadIdx.x;
    int wave = tid >> 6, lane = tid & 63;
    int wr = wave >> 1, wc = wave & 1;
    int l16 = lane & 15, q = lane >> 4;
    int m0 = blockIdx.x * 128, n0 = blockIdx.y * 128;
    int b = m0 >> 11;

    int r0 = tid >> 2, c0 = (tid & 3) * 8;  // rows 0..63 / cols 0..31 (x8)
    us* lA0 = &As[0][wave * 512];
    us* lA1 = &As[0][2048 + wave * 512];
    us* lB0 = &Bs[0][wave * 512];
    us* lB1 = &Bs[0][2048 + wave * 512];
    // A half-1 (k<1024): row m0+b+1+r, col k0;  half-2: row m0+b+r, col k0-1024
    const us* gA1_0 = xall + (size_t)(m0 + b + 1 + r0) * 1024 + c0;
    const us* gA1_1 = xall + (size_t)(m0 + b + 1 + 64 + r0) * 1024 + c0;
    const us* gA2_0 = xall + (size_t)(m0 + b + r0) * 1024 + c0 - 1024;
    const us* gA2_1 = xall + (size_t)(m0 + b + 64 + r0) * 1024 + c0 - 1024;
    const us* gB0 = WfT + (size_t)(n0 + r0) * 2048 + c0;
    const us* gB1 = WfT + (size_t)(n0 + 64 + r0) * 2048 + c0;

    f32x4 acc[4][4] = {};

    // prologue: buffer 0 <- k0 = 0
    gload_lds16(gA1_0, lA0);
    gload_lds16(gA1_1, lA1);
    gload_lds16(gB0, lB0);
    gload_lds16(gB1, lB1);

    for (int k0 = 0; k0 < 2048; k0 += 32) {
        int cur = (k0 >> 5) & 1, nxt = cur ^ 1;
        __syncthreads();  // drains vmcnt -> cur tile ready; nxt free
        int kn = k0 + 32;
        if (kn < 2048) {
            const us* a0 = (kn < 1024) ? gA1_0 : gA2_0;
            const us* a1 = (kn < 1024) ? gA1_1 : gA2_1;
            gload_lds16(a0 + kn, &As[nxt][wave * 512]);
            gload_lds16(a1 + kn, &As[nxt][2048 + wave * 512]);
            gload_lds16(gB0 + kn, &Bs[nxt][wave * 512]);
            gload_lds16(gB1 + kn, &Bs[nxt][2048 + wave * 512]);
        }
        bf16x8 af[4], bfr[4];
#pragma unroll
        for (int mi = 0; mi < 4; mi++)
            af[mi] = *(const bf16x8*)(&As[cur][(wr * 64 + mi * 16 + l16) * 32 + q * 8]);
#pragma unroll
        for (int ni = 0; ni < 4; ni++)
            bfr[ni] = *(const bf16x8*)(&Bs[cur][(wc * 64 + ni * 16 + l16) * 32 + q * 8]);
#pragma unroll
        for (int mi = 0; mi < 4; mi++)
#pragma unroll
            for (int ni = 0; ni < 4; ni++)
                acc[mi][ni] = __builtin_amdgcn_mfma_f32_16x16x32_bf16(
                    af[mi], bfr[ni], acc[mi][ni], 0, 0, 0);
    }

    int grp = n0 >> 10;
#pragma unroll
    for (int mi = 0; mi < 4; mi++) {
#pragma unroll
        for (int ni = 0; ni < 4; ni++) {
#pragma unroll
            for (int reg = 0; reg < 4; reg++) {
                int row = m0 + wr * 64 + mi * 16 + q * 4 + reg;
                int col = n0 + wc * 64 + ni * 16 + l16;
                float val = acc[mi][ni][reg];
                if (grp < 2) {
                    kvout[(size_t)row * 2048 + col] = f2bf(val);
                } else {
                    val = 1.0f / (1.0f + __expf(-val));
                    rout[(size_t)row * 1024 + (col - 2048)] = f2bf(val);
                }
            }
        }
    }
}

// ---- GEMM2: out[M,1024] fp32 = rwkv (M x 1024) * WoT^T ----
__global__ __launch_bounds__(256) void gemm_out(
    const us* __restrict__ A,
    const us* __restrict__ BT,
    float* __restrict__ Cout) {
    __shared__ __align__(16) us As[2][128 * 32];
    __shared__ __align__(16) us Bs[2][128 * 32];
    int tid = threadIdx.x;
    int wave = tid >> 6, lane = tid & 63;
    int wr = wave >> 1, wc = wave & 1;
    int l16 = lane & 15, q = lane >> 4;
    int m0 = blockIdx.x * 128, n0 = blockIdx.y * 128;

    int r0 = tid >> 2, c0 = (tid & 3) * 8;
    const us* gA0 = A + (size_t)(m0 + r0) * 1024 + c0;
    const us* gA1 = A + (size_t)(m0 + 64 + r0) * 1024 + c0;
    const us* gB0 = BT + (size_t)(n0 + r0) * 1024 + c0;
    const us* gB1 = BT + (size_t)(n0 + 64 + r0) * 1024 + c0;

    f32x4 acc[4][4] = {};

    gload_lds16(gA0, &As[0][wave * 512]);
    gload_lds16(gA1, &As[0][2048 + wave * 512]);
    gload_lds16(gB0, &Bs[0][wave * 512]);
    gload_lds16(gB1, &Bs[0][2048 + wave * 512]);

    for (int k0 = 0; k0 < 1024; k0 += 32) {
        int cur = (k0 >> 5) & 1, nxt = cur ^ 1;
        __syncthreads();
        int kn = k0 + 32;
        if (kn < 1024) {
            gload_lds16(gA0 + kn, &As[nxt][wave * 512]);
            gload_lds16(gA1 + kn, &As[nxt][2048 + wave * 512]);
            gload_lds16(gB0 + kn, &Bs[nxt][wave * 512]);
            gload_lds16(gB1 + kn, &Bs[nxt][2048 + wave * 512]);
        }
        bf16x8 af[4], bfr[4];
#pragma unroll
        for (int mi = 0; mi < 4; mi++)
            af[mi] = *(const bf16x8*)(&As[cur][(wr * 64 + mi * 16 + l16) * 32 + q * 8]);
#pragma unroll
        for (int ni = 0; ni < 4; ni++)
            bfr[ni] = *(const bf16x8*)(&Bs[cur][(wc * 64 + ni * 16 + l16) * 32 + q * 8]);
#pragma unroll
        for (int mi = 0; mi < 4; mi++)
#pragma unroll
            for (int ni = 0; ni < 4; ni++)
                acc[mi][ni] = __builtin_amdgcn_mfma_f32_16x16x32_bf16(
                    af[mi], bfr[ni], acc[mi][ni], 0, 0, 0);
    }

#pragma unroll
    for (int mi = 0; mi < 4; mi++)
#pragma unroll
        for (int ni = 0; ni < 4; ni++)
#pragma unroll
            for (int reg = 0; reg < 4; reg++) {
                int row = m0 + wr * 64 + mi * 16 + q * 4 + reg;
                int col = n0 + wc * 64 + ni * 16 + l16;
                Cout[(size_t)row * 1024 + col] = acc[mi][ni][reg];
            }
}

// ---------------- WKV chunked scan (kv packed stride 2048, r stride 1024) ---
__global__ void wkv_phase1(const us* __restrict__ kvbuf,
                           const float* __restrict__ td_arr,
                           float* __restrict__ laa,
                           float* __restrict__ lbb,
                           float* __restrict__ lpp) {
    int g = blockIdx.x * blockDim.x + threadIdx.x;
    int ch = g & (NCH - 1);
    int c = g >> 13;
    int d = ch & (D_DIM - 1);
    int b = ch >> 10;
    float td = td_arr[d];
    float aa = 0.f, bb = 0.f, pp = -1e30f;
    size_t row = (size_t)b * T_DIM + (size_t)c * CHUNK;
    for (int t = 0; t < CHUNK; t++) {
        size_t rbase = (row + t) * 2048;
        float kt = bf2f(kvbuf[rbase + d]);
        float vt = bf2f(kvbuf[rbase + 1024 + d]);
        float ww2 = pp + td;
        float qq2 = fmaxf(ww2, kt);
        float e1b = __expf(ww2 - qq2);
        float e2b = __expf(kt - qq2);
        aa = e1b * aa + e2b * vt;
        bb = e1b * bb + e2b;
        pp = qq2;
    }
    laa[g] = aa;
    lbb[g] = bb;
    lpp[g] = pp;
}

__global__ void wkv_phase2(const float* __restrict__ aa_in,
                           const float* __restrict__ bb_in,
                           const float* __restrict__ pp_in,
                           const float* __restrict__ td_arr,
                           const float* __restrict__ x,
                           float* __restrict__ laa,
                           float* __restrict__ lbb,
                           float* __restrict__ lpp,
                           float* __restrict__ lastx_out,
                           float* __restrict__ aa_out,
                           float* __restrict__ bb_out,
                           float* __restrict__ pp_out) {
    int ch = blockIdx.x * blockDim.x + threadIdx.x;
    int d = ch & (D_DIM - 1);
    int b = ch >> 10;
    float td = td_arr[d];
    float Ldecay = (float)CHUNK * td;
    float A = aa_in[ch], Bv = bb_in[ch], P = pp_in[ch];
    for (int c = 0; c < NCHUNK; c++) {
        int idx = c * NCH + ch;
        float la = laa[idx], lb = lbb[idx], lp = lpp[idx];
        laa[idx] = A; lbb[idx] = Bv; lpp[idx] = P;
        float Pd = P + Ldecay;
        float q = fmaxf(Pd, lp);
        float e1 = __expf(Pd - q);
        float e2 = __expf(lp - q);
        A = e1 * A + e2 * la;
        Bv = e1 * Bv + e2 * lb;
        P = q;
    }
    aa_out[ch] = A;
    bb_out[ch] = Bv;
    pp_out[ch] = P;
    lastx_out[ch] =
        x[(size_t)b * T_DIM * D_DIM + (size_t)(T_DIM - 1) * D_DIM + d];
}

// phase3: replay chunk, rwkv overwrites r in place (same element)
__global__ void wkv_phase3(const us* __restrict__ kvbuf,
                           us* __restrict__ rbuf,
                           const float* __restrict__ tf_arr,
                           const float* __restrict__ td_arr,
                           const float* __restrict__ laa,
                           const float* __restrict__ lbb,
                           const float* __restrict__ lpp) {
    int g = blockIdx.x * blockDim.x + threadIdx.x;
    int ch = g & (NCH - 1);
    int c = g >> 13;
    int d = ch & (D_DIM - 1);
    int b = ch >> 10;
    float tf = tf_arr[d], td = td_arr[d];
    float aa = laa[g], bb = lbb[g], pp = lpp[g];
    size_t row = (size_t)b * T_DIM + (size_t)c * CHUNK;
    for (int t = 0; t < CHUNK; t++) {
        size_t rbase = (row + t) * 2048;
        size_t ridx = (row + t) * 1024 + d;
        float kt = bf2f(kvbuf[rbase + d]);
        float vt = bf2f(kvbuf[rbase + 1024 + d]);
        float rt = bf2f(rbuf[ridx]);
        float ww = tf + kt;
        float qq = fmaxf(pp, ww);
        float e1 = __expf(pp - qq);
        float e2 = __expf(ww - qq);
        float wkv = (e1 * aa + e2 * vt) / (e1 * bb + e2);
        rbuf[ridx] = f2bf(rt * wkv);
        float ww2 = pp + td;
        float qq2 = fmaxf(ww2, kt);
        float e1b = __expf(ww2 - qq2);
        float e2b = __expf(kt - qq2);
        aa = e1b * aa + e2b * vt;
        bb = e1b * bb + e2b;
        pp = qq2;
    }
}

extern "C" void kernel_launch(void* const* d_in, const int* in_sizes, int n_in,
                              void* d_out, int out_size, void* d_ws,
                              size_t ws_size, hipStream_t stream) {
    const float* x      = (const float*)d_in[0];
    const float* last_x = (const float*)d_in[1];
    const float* aa     = (const float*)d_in[2];
    const float* bb     = (const float*)d_in[3];
    const float* pp     = (const float*)d_in[4];
    const float* tmk    = (const float*)d_in[5];
    const float* tmv    = (const float*)d_in[6];
    const float* tmr    = (const float*)d_in[7];
    const float* tf     = (const float*)d_in[8];
    const float* td     = (const float*)d_in[9];
    const float* Wk     = (const float*)d_in[10];
    const float* Wv     = (const float*)d_in[11];
    const float* Wr     = (const float*)d_in[12];
    const float* Wo     = (const float*)d_in[13];

    // workspace: WfT 12.6MB | WoT 2MB | xall 33.6MB | rb 33.6MB  (~82 MB)
    us* WfT  = (us*)d_ws;
    us* WoT  = WfT + (size_t)3072 * 2048;
    us* xall = WoT + (size_t)D_DIM * D_DIM;
    us* rb   = xall + (size_t)B_DIM * (T_DIM + 1) * D_DIM;

    // chunk states alias xall (dead after gemm_fused); 6 MB << 33.6 MB
    float* laa = (float*)xall;
    float* lbb = laa + (size_t)NCH * NCHUNK;
    float* lpp = lbb + (size_t)NCH * NCHUNK;

    float* out       = (float*)d_out;
    float* lastx_out = out + (size_t)M_DIM * D_DIM;
    float* aa_out    = lastx_out + B_DIM * D_DIM;
    float* bb_out    = aa_out + B_DIM * D_DIM;
    float* pp_out    = bb_out + B_DIM * D_DIM;

    // k|v scratch (bf16, M x 2048) lives in the out region of d_out:
    // exactly M*1024*4 bytes; overwritten by gemm_out at the end.
    us* kvbuf = (us*)d_out;

    prep_weights<<<dim3(32, 32, 3), dim3(32, 8), 0, stream>>>(
        Wk, Wv, Wr, tmk, tmv, tmr, WfT);
    transpose_wo<<<dim3(32, 32), dim3(32, 8), 0, stream>>>(Wo, WoT);
    cast_x<<<B_DIM * (T_DIM + 1), 256, 0, stream>>>(x, last_x, xall);

    gemm_fused<<<dim3(M_DIM / 128, 3072 / 128), 256, 0, stream>>>(
        xall, WfT, kvbuf, rb);

    wkv_phase1<<<(NCH * NCHUNK) / 256, 256, 0, stream>>>(kvbuf, td, laa, lbb, lpp);
    wkv_phase2<<<NCH / 256, 256, 0, stream>>>(aa, bb, pp, td, x, laa, lbb, lpp,
                                              lastx_out, aa_out, bb_out, pp_out);
    wkv_phase3<<<(NCH * NCHUNK) / 256, 256, 0, stream>>>(
        kvbuf, rb, tf, td, laa, lbb, lpp);

    gemm_out<<<dim3(M_DIM / 128, D_DIM / 128), 256, 0, stream>>>(rb, WoT, out);
}